// Round 21
// baseline (342.024 us; speedup 1.0000x reference)
//
#include <hip/hip_runtime.h>
#include <hip/hip_bf16.h>
#include <float.h>
#include <math.h>

// ---------------------------------------------------------------------------
// B=8, NCH=4, NPTS=1024, NGT=10, NANCH=5120, M=128, NPOOL=64, EXT=0.2
// NEW_CENTERS: (0,0,1),(0,0,-1),(2.5,0,-1),(2.5,0,1),(2.5,0,0)
// (round-20 best + rp2 counted-vmcnt 3-buffer pipeline)
// ---------------------------------------------------------------------------

typedef __attribute__((ext_vector_type(8))) short short8;
typedef __attribute__((ext_vector_type(4))) float f32x4;

// ---- DPP 16-lane-row reductions ----
template <int CTRL>
__device__ __forceinline__ float dppmv(float x) {
  return __int_as_float(__builtin_amdgcn_update_dpp(
      0, __float_as_int(x), CTRL, 0xF, 0xF, true));
}
__device__ __forceinline__ float dpp_sum16(float x) {
  x += dppmv<0xB1>(x);
  x += dppmv<0x4E>(x);
  x += dppmv<0x124>(x);
  x += dppmv<0x128>(x);
  return x;
}

// ---- async global->LDS staging, 16B per lane (wave-uniform LDS base) -------
__device__ __forceinline__ void stage1k(const unsigned short* g, unsigned short* l) {
  __builtin_amdgcn_global_load_lds(
      (const __attribute__((address_space(1))) unsigned int*)g,
      (__attribute__((address_space(3))) unsigned int*)l, 16, 0, 0);
}

#define FMA16()                                                                 \
  do {                                                                          \
    float4 av = *(const float4*)&sWT[cc][to * 4];                               \
    float4 bv = *(const float4*)&sB[cc][tk * 4];                                \
    acc[0][0] = fmaf(av.x, bv.x, acc[0][0]);                                    \
    acc[0][1] = fmaf(av.x, bv.y, acc[0][1]);                                    \
    acc[0][2] = fmaf(av.x, bv.z, acc[0][2]);                                    \
    acc[0][3] = fmaf(av.x, bv.w, acc[0][3]);                                    \
    acc[1][0] = fmaf(av.y, bv.x, acc[1][0]);                                    \
    acc[1][1] = fmaf(av.y, bv.y, acc[1][1]);                                    \
    acc[1][2] = fmaf(av.y, bv.z, acc[1][2]);                                    \
    acc[1][3] = fmaf(av.y, bv.w, acc[1][3]);                                    \
    acc[2][0] = fmaf(av.z, bv.x, acc[2][0]);                                    \
    acc[2][1] = fmaf(av.z, bv.y, acc[2][1]);                                    \
    acc[2][2] = fmaf(av.z, bv.z, acc[2][2]);                                    \
    acc[2][3] = fmaf(av.z, bv.w, acc[2][3]);                                    \
    acc[3][0] = fmaf(av.w, bv.x, acc[3][0]);                                    \
    acc[3][1] = fmaf(av.w, bv.y, acc[3][1]);                                    \
    acc[3][2] = fmaf(av.w, bv.z, acc[3][2]);                                    \
    acc[3][3] = fmaf(av.w, bv.w, acc[3][3]);                                    \
  } while (0)

// ---------------- pointnet 1x1 conv (+optional input affine/relu) -----------
template <int C, int O, bool AFF, bool RELU, bool TRANS>
__global__ __launch_bounds__(256) void conv_pn(const float* __restrict__ in,
                                               const float* __restrict__ w,
                                               const float* __restrict__ bias,
                                               const float* __restrict__ aff,
                                               float* __restrict__ out) {
  __shared__ __align__(16) float sB[64][68];
  __shared__ __align__(16) float sWT[64][68];
  const int i0 = blockIdx.x * 64;
  const int o0 = blockIdx.y * 64;
  const int b = blockIdx.z;
  const int tid = threadIdx.x;
  const int tk = tid & 15, to = tid >> 4;
  float acc[4][4] = {};
  for (int c0 = 0; c0 < C; c0 += 64) {
    const int cs = (C - c0 < 64) ? (C - c0) : 64;
    for (int idx = tid; idx < 4096; idx += 256) {
      int ii = idx & 63, cc = idx >> 6;
      float v = 0.f;
      if (cc < cs) {
        int c = c0 + cc;
        v = in[(b * C + c) * 1024 + i0 + ii];
        if (AFF) v = fmaf(v, aff[c], aff[C + c]);
        if (RELU) v = fmaxf(v, 0.f);
      }
      sB[cc][ii] = v;
    }
    for (int idx = tid; idx < 4096; idx += 256) {
      int cc = idx & 63, oo = idx >> 6;
      sWT[cc][oo] = (cc < cs) ? w[(o0 + oo) * C + c0 + cc] : 0.f;
    }
    __syncthreads();
    for (int cc = 0; cc < cs; ++cc) { FMA16(); }
    __syncthreads();
  }
  if (TRANS) {
    float b0 = bias[o0 + to * 4], b1 = bias[o0 + to * 4 + 1];
    float b2 = bias[o0 + to * 4 + 2], b3 = bias[o0 + to * 4 + 3];
#pragma unroll
    for (int jj = 0; jj < 4; ++jj) {
      float4 v = make_float4(acc[0][jj] + b0, acc[1][jj] + b1, acc[2][jj] + b2, acc[3][jj] + b3);
      *(float4*)&out[((size_t)(b * 1024) + i0 + tk * 4 + jj) * O + o0 + to * 4] = v;
    }
  } else {
    for (int j = 0; j < 4; ++j) {
      int o = o0 + to * 4 + j;
      float bs = bias[o];
      float4 v = make_float4(acc[j][0] + bs, acc[j][1] + bs, acc[j][2] + bs, acc[j][3] + bs);
      *(float4*)&out[(b * O + o) * 1024 + i0 + tk * 4] = v;
    }
  }
}

// ---------------- BN stats over (B=8, N=1024) per channel -> affine ---------
__global__ __launch_bounds__(256) void bn_stats(const float* __restrict__ x,
                                                const float* __restrict__ g,
                                                const float* __restrict__ be,
                                                float* __restrict__ aff, int C) {
#pragma clang fp contract(off)
  int c = blockIdx.x;
  int tid = threadIdx.x;
  float s = 0.f, q = 0.f;
  for (int idx = tid; idx < 8192; idx += 256) {
    int b = idx >> 10, i = idx & 1023;
    float v = x[(b * C + c) * 1024 + i];
    s += v;
    q += v * v;
  }
  for (int m = 1; m < 64; m <<= 1) {
    s += __shfl_xor(s, m);
    q += __shfl_xor(q, m);
  }
  __shared__ float as_[4], aq_[4];
  int wv = tid >> 6;
  if ((tid & 63) == 0) { as_[wv] = s; aq_[wv] = q; }
  __syncthreads();
  if (tid == 0) {
    s = as_[0] + as_[1] + as_[2] + as_[3];
    q = aq_[0] + aq_[1] + aq_[2] + aq_[3];
    float m_ = s * (1.f / 8192.f);
    float var = q * (1.f / 8192.f) - m_ * m_;
    float A = g[c] / sqrtf(var + 1e-5f);
    aff[c] = A;
    aff[C + c] = be[c] - m_ * A;
  }
}

// ---- predicated register-array insert: ox[p]=vx if p<8, all-static indices -
__device__ __forceinline__ void poly_ins(float* ox, float* oz, int p, float vx, float vz) {
#pragma unroll
  for (int s = 0; s < 8; ++s)
    if (p == s) { ox[s] = vx; oz[s] = vz; }
}

// ---------------- BEV IoU: statically-unrolled clip (register-resident) -----
__device__ float bev_iou_ga(const float* gx, const float* gz, float garea, float ax, float az) {
#pragma clang fp contract(off)
  float px[8], pz[8];
#pragma unroll
  for (int i = 0; i < 4; ++i) {
    px[i] = gx[i];
    pz[i] = gz[i];
    px[i + 4] = 0.f;
    pz[i + 4] = 0.f;
  }
  int count = 4;
  float kx[4], kz[4];
  kx[0] = ax + 1.f;  kz[0] = az + 2.5f;
  kx[1] = ax - 1.f;  kz[1] = az + 2.5f;
  kx[2] = ax - 1.f;  kz[2] = az - 2.5f;
  kx[3] = ax + 1.f;  kz[3] = az - 2.5f;
#pragma unroll
  for (int e = 0; e < 4; ++e) {
    float e1x = kx[e], e1z = kz[e];
    float e2x = kx[(e + 1) & 3], e2z = kz[(e + 1) & 3];
    float ex = e2x - e1x, ez = e2z - e1z;
    int cnt = count > 1 ? count : 1;
    int lim = count < 8 ? count : 8;
    float ox[8] = {}, oz[8] = {};
    int p = 0;
#pragma unroll
    for (int idx = 0; idx < 8; ++idx) {
      if (idx < lim) {
        const int nis = (idx + 1 > 7) ? 7 : idx + 1;  // compile-time index
        float nx = px[nis], nz = pz[nis];
        if (idx + 1 == cnt) { nx = px[0]; nz = pz[0]; }
        float cx = px[idx], cz = pz[idx];
        float dc = ex * (cz - e1z) - ez * (cx - e1x);
        float dn = ex * (nz - e1z) - ez * (nx - e1x);
        bool ic = dc >= 0.f, in_ = dn >= 0.f;
        if (ic) {
          poly_ins(ox, oz, p, cx, cz);
          ++p;
        }
        if (ic != in_) {
          float den = dc - dn;
          float t = dc / (fabsf(den) < 1e-9f ? 1e-9f : den);
          poly_ins(ox, oz, p, cx + t * (nx - cx), cz + t * (nz - cz));
          ++p;
        }
      }
    }
    count = p;
    int cp = p < 8 ? p : 8;
#pragma unroll
    for (int i = 0; i < 8; ++i) {
      px[i] = (i < cp) ? ox[i] : 0.f;
      pz[i] = (i < cp) ? oz[i] : 0.f;
    }
  }
  int cnt = count > 1 ? count : 1;
  int lim = count < 8 ? count : 8;
  float ssum = 0.f;
#pragma unroll
  for (int idx = 0; idx < 8; ++idx) {
    if (idx < lim) {
      const int nis = (idx + 1 > 7) ? 7 : idx + 1;
      float nx = px[nis], nz = pz[nis];
      if (idx + 1 == cnt) { nx = px[0]; nz = pz[0]; }
      ssum += px[idx] * nz - nx * pz[idx];
    }
  }
  float inter = 0.5f * fabsf(ssum);
  return inter / fmaxf(garea + 10.f - inter, 1e-8f);
}

// ---------------- fused: conv3 (512 blk) | iou (1600 blk) | prep_w1 (128 blk)
__global__ __launch_bounds__(256) void fused_mid(
    const float* __restrict__ in2, const float* __restrict__ w3,
    const float* __restrict__ b3, const float* __restrict__ aff2,
    float* __restrict__ out3T,
    const float* __restrict__ points, const float* __restrict__ gt,
    float* __restrict__ iou10, float* __restrict__ o_gt, int* __restrict__ rank,
    const float* __restrict__ w1, unsigned short* __restrict__ W1f) {
  __shared__ __align__(16) float sB[64][68];
  __shared__ __align__(16) float sWT[64][68];
  const int bid = blockIdx.x;
  const int tid = threadIdx.x;
  if (bid < 512) {
    // ---- conv3: C=128, O=256, AFF+RELU, TRANS ----
    const int i0 = (bid & 15) * 64;
    const int o0 = ((bid >> 4) & 3) * 64;
    const int b = bid >> 6;
    const int tk = tid & 15, to = tid >> 4;
    float acc[4][4] = {};
    for (int c0 = 0; c0 < 128; c0 += 64) {
      for (int idx = tid; idx < 4096; idx += 256) {
        int ii = idx & 63, cc = idx >> 6;
        int c = c0 + cc;
        float v = in2[(b * 128 + c) * 1024 + i0 + ii];
        v = fmaf(v, aff2[c], aff2[128 + c]);
        v = fmaxf(v, 0.f);
        sB[cc][ii] = v;
      }
      for (int idx = tid; idx < 4096; idx += 256) {
        int cc = idx & 63, oo = idx >> 6;
        sWT[cc][oo] = w3[(o0 + oo) * 128 + c0 + cc];
      }
      __syncthreads();
      for (int cc = 0; cc < 64; ++cc) { FMA16(); }
      __syncthreads();
    }
    float c0v = b3[o0 + to * 4], c1v = b3[o0 + to * 4 + 1];
    float c2v = b3[o0 + to * 4 + 2], c3v = b3[o0 + to * 4 + 3];
#pragma unroll
    for (int jj = 0; jj < 4; ++jj) {
      float4 v = make_float4(acc[0][jj] + c0v, acc[1][jj] + c1v, acc[2][jj] + c2v, acc[3][jj] + c3v);
      *(float4*)&out3T[((size_t)(b * 1024) + i0 + tk * 4 + jj) * 256 + o0 + to * 4] = v;
    }
  } else if (bid < 2112) {
#pragma clang fp contract(off)
    // ---- iou + folded init (rank zero + o_gt copy) ----
    int r = bid - 512;
    int g = r / 160;
    int rb = r % 160;
    int b = rb / 20;
    int axb = rb % 20;
    int a = axb * 256 + tid;
    if (g == 0) rank[b * 5120 + a] = 0;
    if (g == 0 && b == 0 && axb == 0 && tid < 90)
      o_gt[tid] = gt[630 + tid];
    const float* L = gt + b * 90 + g * 9;
    float gxx = L[3], gzz = L[5], gw = L[0], gl = L[2], gth = L[6];
    float c = cosf(gth), s = sinf(gth);
    const float sx[4] = {0.5f, -0.5f, -0.5f, 0.5f};
    const float sz[4] = {0.5f, 0.5f, -0.5f, -0.5f};
    float gcx[4], gcz[4];
#pragma unroll
    for (int k = 0; k < 4; ++k) {
      float lx = sx[k] * gw, lz = sz[k] * gl;
      gcx[k] = gxx + lx * c - lz * s;
      gcz[k] = gzz + lx * s + lz * c;
    }
    float garea = gw * gl;
    int pt = a / 5, j = a % 5;
    const float CX[5] = {0.f, 0.f, 2.5f, 2.5f, 2.5f};
    const float CZ[5] = {1.f, -1.f, -1.f, 1.f, 0.f};
    const float* P = points + b * 4096;
    float ax = P[pt] - CX[j];
    float az = P[2048 + pt] - CZ[j];
    iou10[(size_t)(b * 10 + g) * 5120 + a] = bev_iou_ga(gcx, gcz, garea, ax, az);
  } else {
    // ---- prep_w1: 4 outputs per block, 64 lanes each ----
    int o = (bid - 2112) * 4 + (tid >> 6);
    int lp = tid & 63;
    if (lp < 36) {
      int ks = lp >> 2, quad = lp & 3;
      int tile = o >> 4;
      union { __hip_bfloat16 h[8]; uint4 u; } pk;
#pragma unroll
      for (int j = 0; j < 8; ++j) {
        int c = ks * 32 + quad * 8 + j;
        float v = (c < 259) ? w1[o * 259 + c] : 0.f;
        pk.h[j] = __float2bfloat16(v);
      }
      *(uint4*)&W1f[((size_t)(tile * 9 + ks) * 64 + quad * 16 + (o & 15)) * 8] = pk.u;
    }
  }
}

// ---------------- fused: bn_stats_t (256 blk) | iou_reduce (160 blk) --------
__global__ __launch_bounds__(256) void bn_iou_red(
    const float* __restrict__ x, const float* __restrict__ g,
    const float* __restrict__ be, float* __restrict__ aff,
    const float* __restrict__ iou10, float* __restrict__ maxiou,
    int* __restrict__ maxind) {
  const int bid = blockIdx.x;
  const int tid = threadIdx.x;
  if (bid < 256) {
#pragma clang fp contract(off)
    int c = bid;
    float s = 0.f, q = 0.f;
    for (int idx = tid; idx < 8192; idx += 256) {
      float v = x[(size_t)idx * 256 + c];
      s += v;
      q += v * v;
    }
    for (int m = 1; m < 64; m <<= 1) {
      s += __shfl_xor(s, m);
      q += __shfl_xor(q, m);
    }
    __shared__ float as_[4], aq_[4];
    int wv = tid >> 6;
    if ((tid & 63) == 0) { as_[wv] = s; aq_[wv] = q; }
    __syncthreads();
    if (tid == 0) {
      s = as_[0] + as_[1] + as_[2] + as_[3];
      q = aq_[0] + aq_[1] + aq_[2] + aq_[3];
      float m_ = s * (1.f / 8192.f);
      float var = q * (1.f / 8192.f) - m_ * m_;
      float A = g[c] / sqrtf(var + 1e-5f);
      aff[c] = A;
      aff[256 + c] = be[c] - m_ * A;
    }
  } else {
    int r = bid - 256;
    int b = r / 20;
    int a = (r % 20) * 256 + tid;
    float best = -1.f;
    int bi = 0;
    for (int g2 = 0; g2 < 10; ++g2) {
      float v = iou10[(size_t)(b * 10 + g2) * 5120 + a];
      if (v > best) { best = v; bi = g2; }
    }
    maxiou[b * 5120 + a] = best;
    maxind[b * 5120 + a] = bi;
  }
}

// ---------------- rank: partial counts over j-chunks (round-15 form) --------
__global__ __launch_bounds__(256) void select_rank(const float* __restrict__ maxiou,
                                                   int* __restrict__ rank) {
  __shared__ __align__(16) float vals[640];
  int b = blockIdx.y, chunk = blockIdx.z, tid = threadIdx.x;
  int jb0 = chunk * 640;
  for (int i = tid; i < 640; i += 256) vals[i] = maxiou[b * 5120 + jb0 + i];
  int a = blockIdx.x * 256 + tid;
  float av = maxiou[b * 5120 + a];
  __syncthreads();
  int rk = 0;
#pragma unroll 4
  for (int j4 = 0; j4 < 160; ++j4) {
    float4 v = *(const float4*)&vals[j4 * 4];
    int jb = jb0 + j4 * 4;
    rk += (v.x < av) || (v.x == av && jb < a);
    rk += (v.y < av) || (v.y == av && jb + 1 < a);
    rk += (v.z < av) || (v.z == av && jb + 2 < a);
    rk += (v.w < av) || (v.w == av && jb + 3 < a);
  }
  atomicAdd(&rank[b * 5120 + a], rk);
}

// ---------------- write selected rows from final ranks ----------------------
__global__ __launch_bounds__(256) void select_write(const int* __restrict__ rank,
                                                    const float* __restrict__ maxiou,
                                                    const int* __restrict__ maxind,
                                                    const float* __restrict__ points,
                                                    float* __restrict__ o_lbl,
                                                    float* __restrict__ o_iou,
                                                    float* __restrict__ o_box,
                                                    float* __restrict__ o_idx) {
#pragma clang fp contract(off)
  int b = blockIdx.y, tid = threadIdx.x;
  int a = blockIdx.x * 256 + tid;
  int rk = rank[b * 5120 + a];
  int slot = -1;
  if (rk < 64) slot = rk;
  else if (rk >= 5056) slot = rk - 4992;  // 64 + (rk - 5056)
  if (slot >= 0) {
    const float CX[5] = {0.f, 0.f, 2.5f, 2.5f, 2.5f};
    const float CZ[5] = {1.f, -1.f, -1.f, 1.f, 0.f};
    int base = b * 128 + slot;
    float av = maxiou[b * 5120 + a];
    o_iou[base] = av;
    o_lbl[base] = av > 0.5f ? 1.f : 0.f;
    o_idx[base] = (float)maxind[b * 5120 + a];
    int pt = a / 5, j = a % 5;
    const float* P = points + b * 4096;
    float* bx = o_box + base * 7;
    bx[0] = P[pt] - CX[j];
    bx[1] = P[1024 + pt];
    bx[2] = P[2048 + pt] - CZ[j];
    bx[3] = 2.f;
    bx[4] = 2.f;
    bx[5] = 5.f;
    bx[6] = 0.f;
  }
}

// ---- pool inside-test, fp-contract off (bit-exact vs old pool_kernel) ------
__device__ __forceinline__ bool pool_inside(const float* __restrict__ P,
                                            const float* bx, int pt) {
#pragma clang fp contract(off)
  float limx = bx[4] * 0.5f + 0.2f, limz = bx[5] * 0.5f + 0.2f;
  float ylo = bx[1] - bx[3] - 0.2f, yhi = bx[1] + 0.2f;
  float dx = P[pt] - bx[0];
  float py = P[1024 + pt];
  float dz = P[2048 + pt] - bx[2];
  return (fabsf(dx) < limx) && (fabsf(dz) < limz) && (py > ylo) && (py < yhi);
}

// ---------------- fused pool + gather + rp1 (pff lives only in LDS) ---------
__global__ __launch_bounds__(1024) void gather_rp1(
    const float* __restrict__ out3T, const float* __restrict__ points,
    const float* __restrict__ selboxes, const float* __restrict__ aff3,
    const float* __restrict__ bias1, const unsigned short* __restrict__ W1f,
    unsigned short* __restrict__ g1x,
    float* __restrict__ psum4, float* __restrict__ psq4) {
  __shared__ __align__(16) unsigned short sBuf[18432];  // 36KB B-tile
  __shared__ int sSel[64];
  __shared__ float sBox[8];
  __shared__ float sA3[256], sB3[256];
  __shared__ int wcnt[16];
  const int bm = blockIdx.x;
  const int b = bm >> 7;
  const int tid = threadIdx.x;
  if (tid < 7) sBox[tid] = selboxes[bm * 7 + tid];
  if (tid >= 256 && tid < 512) sA3[tid - 256] = aff3[tid - 256];
  if (tid >= 512 && tid < 768) sB3[tid - 512] = aff3[256 + tid - 512];
  __syncthreads();
  // -------- phase 0: pool (pt = tid, 16 waves x 64 lanes) --------
  {
    const float* P = points + b * 4096;
    const int lane = tid & 63, w16 = tid >> 6;
    bool ins = pool_inside(P, sBox, tid);
    unsigned long long mw = __ballot(ins);
    if (lane == 0) wcnt[w16] = __popcll(mw);
    __syncthreads();
    int cumw = 0, total = 0;
#pragma unroll
    for (int i = 0; i < 16; ++i) {
      int c = wcnt[i];
      total += c;
      if (i < w16) cumw += c;
    }
    int inbefore = cumw + __popcll(mw & ((1ull << lane) - 1));
    int slot = ins ? inbefore : total + (tid - inbefore);
    if (slot < 64) sSel[slot] = tid | (ins ? 0x10000 : 0);
    __syncthreads();
  }
  // -------- phase 1: gather into LDS --------
  for (int u = tid; u < 2304; u += 1024) {
    int ks, pool, part;
    if (u < 2048) {
      ks = u >> 8;
      int rem = u & 255;
      pool = rem >> 2;
      part = rem & 3;
    } else {
      int v = u - 2048;
      ks = 8;
      pool = v >> 2;
      part = v & 3;
    }
    const int ni = pool >> 4, nib = pool & 15;
    const int sv = sSel[pool];
    const int pt = sv & 0xFFFF;
    const bool valid = (sv >> 16) != 0;
    union { __hip_bfloat16 h[8]; uint4 uu; } pk;
    if (ks < 8) {
      const float* row = out3T + ((size_t)(b << 10) + pt) * 256;
      int c0 = ks * 32 + part * 8;
      float4 x0 = *(const float4*)&row[c0];
      float4 x1 = *(const float4*)&row[c0 + 4];
      float v[8] = {x0.x, x0.y, x0.z, x0.w, x1.x, x1.y, x1.z, x1.w};
#pragma unroll
      for (int e = 0; e < 8; ++e) {
        float vv = valid ? fmaf(v[e], sA3[c0 + e], sB3[c0 + e]) : 0.f;
        pk.h[e] = __float2bfloat16(vv);
      }
    } else {
#pragma unroll
      for (int e = 0; e < 8; ++e) pk.h[e] = __float2bfloat16(0.f);
      if (part == 0) {
#pragma unroll
        for (int d = 0; d < 3; ++d) {
          float pv = valid ? points[(b * 4 + d) * 1024 + pt] : 0.f;
          pk.h[d] = __float2bfloat16(pv - sBox[d]);
        }
      }
    }
    *(uint4*)&sBuf[(size_t)(((ks * 4 + ni) * 64) + part * 16 + nib) * 8] = pk.uu;
  }
  __syncthreads();
  // -------- phase 2: rp1 MFMA (16 waves, mi=2) --------
  const int lane = tid & 63, wv = tid >> 6;
  const int ot = wv >> 2, w = wv & 3;
  const int quad = lane >> 4, nib = lane & 15;
  const unsigned short* Aw = &W1f[((size_t)(ot * 8 + w * 2) * 9 * 64 + lane) * 8];
  const unsigned short* Bl = &sBuf[lane * 8];
  f32x4 acc[2][4] = {};
#pragma unroll
  for (int ks = 0; ks < 9; ++ks) {
    short8 af[2], bf[4];
#pragma unroll
    for (int mi = 0; mi < 2; ++mi)
      af[mi] = *(const short8*)&Aw[(size_t)(mi * 9 + ks) * 512];
#pragma unroll
    for (int ni = 0; ni < 4; ++ni)
      bf[ni] = *(const short8*)&Bl[(size_t)(ks * 4 + ni) * 512];
#pragma unroll
    for (int mi = 0; mi < 2; ++mi)
#pragma unroll
      for (int ni = 0; ni < 4; ++ni)
        acc[mi][ni] = __builtin_amdgcn_mfma_f32_16x16x32_bf16(af[mi], bf[ni], acc[mi][ni], 0, 0, 0);
  }
  const int cbase = ot * 128 + w * 32;
#pragma unroll
  for (int mi = 0; mi < 2; ++mi) {
    float bv[4];
#pragma unroll
    for (int r = 0; r < 4; ++r) bv[r] = bias1[cbase + mi * 16 + quad * 4 + r];
    float s[4] = {0.f, 0.f, 0.f, 0.f}, q[4] = {0.f, 0.f, 0.f, 0.f};
    const int kgbase = (cbase + mi * 16) >> 3;
#pragma unroll
    for (int ni = 0; ni < 4; ++ni) {
      union { __hip_bfloat16 h[4]; unsigned int u[2]; } pk;
#pragma unroll
      for (int r = 0; r < 4; ++r) {
        float v = acc[mi][ni][r] + bv[r];
        pk.h[r] = __float2bfloat16(v);
        s[r] += v;
        q[r] += v * v;
      }
      unsigned int p0 = (unsigned int)__shfl_xor((int)pk.u[0], 16);
      unsigned int p1 = (unsigned int)__shfl_xor((int)pk.u[1], 16);
      if ((quad & 1) == 0) {
        uint4 g = make_uint4(pk.u[0], pk.u[1], p0, p1);
        int kg = kgbase + (quad >> 1);
        *(uint4*)&g1x[((size_t)(bm * 64 + kg) * 64 + ni * 16 + nib) * 8] = g;
      }
    }
#pragma unroll
    for (int r = 0; r < 4; ++r) {
      float ss = dpp_sum16(s[r]);
      float qq = dpp_sum16(q[r]);
      if (nib == 0) {
        int o = cbase + mi * 16 + quad * 4 + r;
        psum4[(size_t)o * 1024 + bm] = ss;
        psq4[(size_t)o * 1024 + bm] = qq;
      }
    }
  }
}

// ---------------- BN affine from per-bm partials, [o][bm] layout ------------
__global__ __launch_bounds__(64) void bn_aff_part(const float* __restrict__ psum,
                                                  const float* __restrict__ psq,
                                                  const float* __restrict__ g,
                                                  const float* __restrict__ be,
                                                  float* __restrict__ aff, int C) {
#pragma clang fp contract(off)
  int o = blockIdx.x;
  int lane = threadIdx.x;
  float s = 0.f, q = 0.f;
  for (int i = 0; i < 16; ++i) {
    int bm = i * 64 + lane;
    s += psum[(size_t)o * 1024 + bm];
    q += psq[(size_t)o * 1024 + bm];
  }
  for (int m = 1; m < 64; m <<= 1) {
    s += __shfl_xor(s, m);
    q += __shfl_xor(q, m);
  }
  if (lane == 0) {
    float m_ = s * (1.f / 65536.f);
    float var = q * (1.f / 65536.f) - m_ * m_;
    float A = g[o] / sqrtf(var + 1e-5f);
    aff[o] = A;
    aff[C + o] = be[o] - m_ * A;
  }
}

// ---------------- prep W2: fold BN4, A-fragment order [tile64][ks16][lane][8]
__global__ __launch_bounds__(64) void prep_w2(const float* __restrict__ w2,
                                              const float* __restrict__ b2,
                                              const float* __restrict__ aff4,
                                              unsigned short* __restrict__ W2f,
                                              float* __restrict__ bias2p) {
  int o = blockIdx.x;
  int lp = threadIdx.x;
  int ks = lp >> 2, quad = lp & 3;
  int tile = o >> 4;
  float accb = 0.f;
  union { __hip_bfloat16 h[8]; uint4 u; } pk;
#pragma unroll
  for (int j = 0; j < 8; ++j) {
    int c = ks * 32 + quad * 8 + j;
    float wv = w2[o * 512 + c];
    pk.h[j] = __float2bfloat16(wv * aff4[c]);
    accb += wv * aff4[512 + c];
  }
  *(uint4*)&W2f[((size_t)(tile * 16 + ks) * 64 + quad * 16 + (o & 15)) * 8] = pk.u;
  for (int m = 1; m < 64; m <<= 1) accb += __shfl_xor(accb, m);
  if (lp == 0) bias2p[o] = b2[o] + accb;
}

// ---------------- rp2: counted-vmcnt 3-buffer pipeline (T4) -----------------
// s_waitcnt vmcnt(4) + raw s_barrier per chunk: the prefetch for chunk c+1
// stays IN FLIGHT across the barrier (old __syncthreads drained vmcnt to 0).
// 3 x 16KB buffers; chunk c lives in buf[c%3]; stage c+2 after the barrier
// that guarantees all waves finished computing c-1 (whose buffer it reuses).
__global__ __launch_bounds__(256) void rp2_mfma(const unsigned short* __restrict__ W2f,
                                                const unsigned short* __restrict__ g1x,
                                                const float* __restrict__ bias2p,
                                                float* __restrict__ maxb,
                                                float* __restrict__ minb,
                                                float* __restrict__ psum,
                                                float* __restrict__ psq) {
  __shared__ __align__(16) unsigned short sBuf[3][8192];  // 48KB LDS
  const int tid = threadIdx.x;
  const int lane = tid & 63, w = tid >> 6;
  const int quad = lane >> 4, nib = lane & 15;
  const int l = blockIdx.x;            // 4096 blocks
  const int xcd = l & 7;
  const int j = l >> 3;                // 0..511
  const int ot = j & 3;
  const int bm = xcd * 128 + (j >> 2);
  const unsigned short* Aw = &W2f[((size_t)(ot * 4 + w) * 4 * 16 * 64 + lane) * 8];
  const unsigned short* Bg = g1x + (size_t)bm * 32768 + w * 2048 + lane * 8;
  // prologue: stage chunks 0 and 1 (8 loads/wave in flight)
#pragma unroll
  for (int i = 0; i < 4; ++i)
    stage1k(Bg + i * 512, &sBuf[0][w * 2048 + i * 512]);
#pragma unroll
  for (int i = 0; i < 4; ++i)
    stage1k(Bg + 8192 + i * 512, &sBuf[1][w * 2048 + i * 512]);
  f32x4 acc[4][4] = {};  // acc[pi][oi]: rows = pools, cols = o
#pragma unroll
  for (int c = 0; c < 4; ++c) {
    if (c < 3) {
      asm volatile("s_waitcnt vmcnt(4)" ::: "memory");  // chunk c landed; c+1 in flight
    } else {
      asm volatile("s_waitcnt vmcnt(0)" ::: "memory");  // tail: drain last chunk
    }
    __builtin_amdgcn_s_barrier();      // raw barrier: no implicit vmcnt drain
    if (c < 2) {
      // buf[(c+2)%3] held chunk c-1; all waves finished reading it before
      // the barrier above (compute c-1 precedes it in every wave).
#pragma unroll
      for (int i = 0; i < 4; ++i)
        stage1k(Bg + (c + 2) * 8192 + i * 512, &sBuf[(c + 2) % 3][w * 2048 + i * 512]);
    }
    const unsigned short* Bl = &sBuf[c % 3][quad * 512 + nib * 8];
#pragma unroll
    for (int k2 = 0; k2 < 4; ++k2) {
      const int ks = c * 4 + k2;
      short8 af[4], bf[4];
#pragma unroll
      for (int mi = 0; mi < 4; ++mi)
        af[mi] = *(const short8*)&Aw[(size_t)(mi * 16 + ks) * 512];
#pragma unroll
      for (int ni = 0; ni < 4; ++ni)
        bf[ni] = *(const short8*)&Bl[(size_t)(k2 * 2048 + ni * 128)];
#pragma unroll
      for (int mi = 0; mi < 4; ++mi)
#pragma unroll
        for (int ni = 0; ni < 4; ++ni)
          acc[ni][mi] = __builtin_amdgcn_mfma_f32_16x16x32_bf16(bf[ni], af[mi], acc[ni][mi], 0, 0, 0);
    }
  }
  const int obase = ot * 256 + w * 64;
#pragma unroll
  for (int oi = 0; oi < 4; ++oi) {
    int o = obase + oi * 16 + nib;
    float bs = bias2p[o];
    float mx = -FLT_MAX, mn = FLT_MAX, s = 0.f, q = 0.f;
#pragma unroll
    for (int pi = 0; pi < 4; ++pi) {
#pragma unroll
      for (int r = 0; r < 4; ++r) {
        float v = acc[pi][oi][r] + bs;
        mx = fmaxf(mx, v);
        mn = fminf(mn, v);
        s += v;
        q += v * v;
      }
    }
    mx = fmaxf(mx, __shfl_xor(mx, 16));
    mx = fmaxf(mx, __shfl_xor(mx, 32));
    mn = fminf(mn, __shfl_xor(mn, 16));
    mn = fminf(mn, __shfl_xor(mn, 32));
    s += __shfl_xor(s, 16);
    s += __shfl_xor(s, 32);
    q += __shfl_xor(q, 16);
    q += __shfl_xor(q, 32);
    if (quad == 0) {
      maxb[bm * 1024 + o] = mx;
      minb[bm * 1024 + o] = mn;
      psum[(size_t)o * 1024 + bm] = s;
      psq[(size_t)o * 1024 + bm] = q;
    }
  }
}

// ---------------- feats: monotone-affine max over NPOOL --------------------
__global__ void feats_kernel(const float* __restrict__ maxb, const float* __restrict__ minb,
                             const float* __restrict__ aff5, float* __restrict__ o_feats) {
#pragma clang fp contract(off)
  int i = blockIdx.x * 256 + threadIdx.x;
  int o = i & 1023;
  float A = aff5[o], Bv = aff5[1024 + o];
  float v = (A >= 0.f) ? maxb[i] : minb[i];
  o_feats[i] = v * A + Bv;
}

// ---------------------------------------------------------------------------
extern "C" void kernel_launch(void* const* d_in, const int* in_sizes, int n_in,
                              void* d_out, int out_size, void* d_ws, size_t ws_size,
                              hipStream_t stream) {
  (void)in_sizes; (void)n_in; (void)out_size; (void)ws_size;
  const float* points = (const float*)d_in[0];
  const float* gt = (const float*)d_in[1];
  const float* pn_w1 = (const float*)d_in[2];
  const float* pn_b1 = (const float*)d_in[3];
  const float* pn_g1 = (const float*)d_in[4];
  const float* pn_be1 = (const float*)d_in[5];
  const float* pn_w2 = (const float*)d_in[6];
  const float* pn_b2 = (const float*)d_in[7];
  const float* pn_g2 = (const float*)d_in[8];
  const float* pn_be2 = (const float*)d_in[9];
  const float* pn_w3 = (const float*)d_in[10];
  const float* pn_b3 = (const float*)d_in[11];
  const float* pn_g3 = (const float*)d_in[12];
  const float* pn_be3 = (const float*)d_in[13];
  const float* rp_w1 = (const float*)d_in[14];
  const float* rp_b1 = (const float*)d_in[15];
  const float* rp_g1 = (const float*)d_in[16];
  const float* rp_be1 = (const float*)d_in[17];
  const float* rp_w2 = (const float*)d_in[18];
  const float* rp_b2 = (const float*)d_in[19];
  const float* rp_g2 = (const float*)d_in[20];
  const float* rp_be2 = (const float*)d_in[21];

  float* ws = (float*)d_ws;
  float* out1 = ws;                        // 524288 f (reused: W2f+bias2p)
  float* out2 = out1 + 524288;             // 1048576 f
  float* maxiou = out2 + 1048576;          // 40960
  int* maxind = (int*)(maxiou + 40960);    // 40960
  int* selpts = maxind + 40960;            // 65536 (unused)
  int* rank = selpts + 65536;              // 40960
  float* aff1 = (float*)(rank + 40960);    // 128
  float* aff2 = aff1 + 128;                // 256
  float* aff3 = aff2 + 256;                // 512
  float* aff4 = aff3 + 512;                // 1024
  float* aff5 = aff4 + 1024;               // 2048
  float* psum4 = aff5 + 2048;              // 524288
  float* psq4 = psum4 + 524288;            // 524288
  unsigned short* W1f = (unsigned short*)(psq4 + 524288);  // 147456 sh = 73728 f
  float* pff_f = (float*)(W1f) + 73728;    // 9437184 f region (pff now LDS-only)
  float* out3T = pff_f;                    // 2097152 f — disjoint from g1x
  float* maxb = pff_f + 2097152;           // 4x1048576 f, after out3T
  float* minb = maxb + 1048576;
  float* psum5 = minb + 1048576;
  float* psq5 = psum5 + 1048576;
  float* g1x_f = pff_f + 9437184;          // g1x: 16777216 f
  unsigned short* g1x = (unsigned short*)g1x_f;
  float* iou10 = g1x_f + 2097152;          // 409600 f, overlaps g1x (dead before gather_rp1)
  unsigned short* W2f = (unsigned short*)out1;
  float* bias2p = out1 + 262144;

  float* o_feats = (float*)d_out;
  float* o_lbl = o_feats + 1048576;
  float* o_iou = o_lbl + 1024;
  float* o_box = o_iou + 1024;
  float* o_gt = o_box + 7168;
  float* o_idx = o_gt + 90;

  conv_pn<4, 64, false, false, false><<<dim3(16, 1, 8), 256, 0, stream>>>(points, pn_w1, pn_b1, nullptr, out1);
  bn_stats<<<64, 256, 0, stream>>>(out1, pn_g1, pn_be1, aff1, 64);
  conv_pn<64, 128, true, true, false><<<dim3(16, 2, 8), 256, 0, stream>>>(out1, pn_w2, pn_b2, aff1, out2);
  bn_stats<<<128, 256, 0, stream>>>(out2, pn_g2, pn_be2, aff2, 128);
  fused_mid<<<2240, 256, 0, stream>>>(out2, pn_w3, pn_b3, aff2, out3T,
                                      points, gt, iou10, o_gt, rank,
                                      rp_w1, W1f);
  bn_iou_red<<<416, 256, 0, stream>>>(out3T, pn_g3, pn_be3, aff3,
                                      iou10, maxiou, maxind);
  select_rank<<<dim3(20, 8, 8), 256, 0, stream>>>(maxiou, rank);
  select_write<<<dim3(20, 8), 256, 0, stream>>>(rank, maxiou, maxind, points, o_lbl, o_iou, o_box, o_idx);
  gather_rp1<<<1024, 1024, 0, stream>>>(out3T, points, o_box, aff3,
                                        rp_b1, W1f, g1x, psum4, psq4);
  bn_aff_part<<<512, 64, 0, stream>>>(psum4, psq4, rp_g1, rp_be1, aff4, 512);
  prep_w2<<<1024, 64, 0, stream>>>(rp_w2, rp_b2, aff4, W2f, bias2p);
  rp2_mfma<<<4096, 256, 0, stream>>>(W2f, g1x, bias2p, maxb, minb, psum5, psq5);
  bn_aff_part<<<1024, 64, 0, stream>>>(psum5, psq5, rp_g2, rp_be2, aff5, 1024);
  feats_kernel<<<4096, 256, 0, stream>>>(maxb, minb, aff5, o_feats);
}

// Round 22
// 333.651 us; speedup vs baseline: 1.0251x; 1.0251x over previous
//
#include <hip/hip_runtime.h>
#include <hip/hip_bf16.h>
#include <float.h>
#include <math.h>

// ---------------------------------------------------------------------------
// B=8, NCH=4, NPTS=1024, NGT=10, NANCH=5120, M=128, NPOOL=64, EXT=0.2
// NEW_CENTERS: (0,0,1),(0,0,-1),(2.5,0,-1),(2.5,0,1),(2.5,0,0)
// (final: round-18/20 measured-best config, 336.9 us)
// rp2 note: 7 restructures all land 72-74us = ~954 TF, the 2-barrier
// structure's documented ceiling; counted-vmcnt (r21) null per regime-gate.
// ---------------------------------------------------------------------------

typedef __attribute__((ext_vector_type(8))) short short8;
typedef __attribute__((ext_vector_type(4))) float f32x4;

// ---- DPP 16-lane-row reductions ----
template <int CTRL>
__device__ __forceinline__ float dppmv(float x) {
  return __int_as_float(__builtin_amdgcn_update_dpp(
      0, __float_as_int(x), CTRL, 0xF, 0xF, true));
}
__device__ __forceinline__ float dpp_sum16(float x) {
  x += dppmv<0xB1>(x);
  x += dppmv<0x4E>(x);
  x += dppmv<0x124>(x);
  x += dppmv<0x128>(x);
  return x;
}

// ---- async global->LDS staging, 16B per lane (wave-uniform LDS base) -------
__device__ __forceinline__ void stage1k(const unsigned short* g, unsigned short* l) {
  __builtin_amdgcn_global_load_lds(
      (const __attribute__((address_space(1))) unsigned int*)g,
      (__attribute__((address_space(3))) unsigned int*)l, 16, 0, 0);
}

#define FMA16()                                                                 \
  do {                                                                          \
    float4 av = *(const float4*)&sWT[cc][to * 4];                               \
    float4 bv = *(const float4*)&sB[cc][tk * 4];                                \
    acc[0][0] = fmaf(av.x, bv.x, acc[0][0]);                                    \
    acc[0][1] = fmaf(av.x, bv.y, acc[0][1]);                                    \
    acc[0][2] = fmaf(av.x, bv.z, acc[0][2]);                                    \
    acc[0][3] = fmaf(av.x, bv.w, acc[0][3]);                                    \
    acc[1][0] = fmaf(av.y, bv.x, acc[1][0]);                                    \
    acc[1][1] = fmaf(av.y, bv.y, acc[1][1]);                                    \
    acc[1][2] = fmaf(av.y, bv.z, acc[1][2]);                                    \
    acc[1][3] = fmaf(av.y, bv.w, acc[1][3]);                                    \
    acc[2][0] = fmaf(av.z, bv.x, acc[2][0]);                                    \
    acc[2][1] = fmaf(av.z, bv.y, acc[2][1]);                                    \
    acc[2][2] = fmaf(av.z, bv.z, acc[2][2]);                                    \
    acc[2][3] = fmaf(av.z, bv.w, acc[2][3]);                                    \
    acc[3][0] = fmaf(av.w, bv.x, acc[3][0]);                                    \
    acc[3][1] = fmaf(av.w, bv.y, acc[3][1]);                                    \
    acc[3][2] = fmaf(av.w, bv.z, acc[3][2]);                                    \
    acc[3][3] = fmaf(av.w, bv.w, acc[3][3]);                                    \
  } while (0)

// ---------------- pointnet 1x1 conv (+optional input affine/relu) -----------
template <int C, int O, bool AFF, bool RELU, bool TRANS>
__global__ __launch_bounds__(256) void conv_pn(const float* __restrict__ in,
                                               const float* __restrict__ w,
                                               const float* __restrict__ bias,
                                               const float* __restrict__ aff,
                                               float* __restrict__ out) {
  __shared__ __align__(16) float sB[64][68];
  __shared__ __align__(16) float sWT[64][68];
  const int i0 = blockIdx.x * 64;
  const int o0 = blockIdx.y * 64;
  const int b = blockIdx.z;
  const int tid = threadIdx.x;
  const int tk = tid & 15, to = tid >> 4;
  float acc[4][4] = {};
  for (int c0 = 0; c0 < C; c0 += 64) {
    const int cs = (C - c0 < 64) ? (C - c0) : 64;
    for (int idx = tid; idx < 4096; idx += 256) {
      int ii = idx & 63, cc = idx >> 6;
      float v = 0.f;
      if (cc < cs) {
        int c = c0 + cc;
        v = in[(b * C + c) * 1024 + i0 + ii];
        if (AFF) v = fmaf(v, aff[c], aff[C + c]);
        if (RELU) v = fmaxf(v, 0.f);
      }
      sB[cc][ii] = v;
    }
    for (int idx = tid; idx < 4096; idx += 256) {
      int cc = idx & 63, oo = idx >> 6;
      sWT[cc][oo] = (cc < cs) ? w[(o0 + oo) * C + c0 + cc] : 0.f;
    }
    __syncthreads();
    for (int cc = 0; cc < cs; ++cc) { FMA16(); }
    __syncthreads();
  }
  if (TRANS) {
    float b0 = bias[o0 + to * 4], b1 = bias[o0 + to * 4 + 1];
    float b2 = bias[o0 + to * 4 + 2], b3 = bias[o0 + to * 4 + 3];
#pragma unroll
    for (int jj = 0; jj < 4; ++jj) {
      float4 v = make_float4(acc[0][jj] + b0, acc[1][jj] + b1, acc[2][jj] + b2, acc[3][jj] + b3);
      *(float4*)&out[((size_t)(b * 1024) + i0 + tk * 4 + jj) * O + o0 + to * 4] = v;
    }
  } else {
    for (int j = 0; j < 4; ++j) {
      int o = o0 + to * 4 + j;
      float bs = bias[o];
      float4 v = make_float4(acc[j][0] + bs, acc[j][1] + bs, acc[j][2] + bs, acc[j][3] + bs);
      *(float4*)&out[(b * O + o) * 1024 + i0 + tk * 4] = v;
    }
  }
}

// ---------------- BN stats over (B=8, N=1024) per channel -> affine ---------
__global__ __launch_bounds__(256) void bn_stats(const float* __restrict__ x,
                                                const float* __restrict__ g,
                                                const float* __restrict__ be,
                                                float* __restrict__ aff, int C) {
#pragma clang fp contract(off)
  int c = blockIdx.x;
  int tid = threadIdx.x;
  float s = 0.f, q = 0.f;
  for (int idx = tid; idx < 8192; idx += 256) {
    int b = idx >> 10, i = idx & 1023;
    float v = x[(b * C + c) * 1024 + i];
    s += v;
    q += v * v;
  }
  for (int m = 1; m < 64; m <<= 1) {
    s += __shfl_xor(s, m);
    q += __shfl_xor(q, m);
  }
  __shared__ float as_[4], aq_[4];
  int wv = tid >> 6;
  if ((tid & 63) == 0) { as_[wv] = s; aq_[wv] = q; }
  __syncthreads();
  if (tid == 0) {
    s = as_[0] + as_[1] + as_[2] + as_[3];
    q = aq_[0] + aq_[1] + aq_[2] + aq_[3];
    float m_ = s * (1.f / 8192.f);
    float var = q * (1.f / 8192.f) - m_ * m_;
    float A = g[c] / sqrtf(var + 1e-5f);
    aff[c] = A;
    aff[C + c] = be[c] - m_ * A;
  }
}

// ---- predicated register-array insert: ox[p]=vx if p<8, all-static indices -
__device__ __forceinline__ void poly_ins(float* ox, float* oz, int p, float vx, float vz) {
#pragma unroll
  for (int s = 0; s < 8; ++s)
    if (p == s) { ox[s] = vx; oz[s] = vz; }
}

// ---------------- BEV IoU: statically-unrolled clip (register-resident) -----
__device__ float bev_iou_ga(const float* gx, const float* gz, float garea, float ax, float az) {
#pragma clang fp contract(off)
  float px[8], pz[8];
#pragma unroll
  for (int i = 0; i < 4; ++i) {
    px[i] = gx[i];
    pz[i] = gz[i];
    px[i + 4] = 0.f;
    pz[i + 4] = 0.f;
  }
  int count = 4;
  float kx[4], kz[4];
  kx[0] = ax + 1.f;  kz[0] = az + 2.5f;
  kx[1] = ax - 1.f;  kz[1] = az + 2.5f;
  kx[2] = ax - 1.f;  kz[2] = az - 2.5f;
  kx[3] = ax + 1.f;  kz[3] = az - 2.5f;
#pragma unroll
  for (int e = 0; e < 4; ++e) {
    float e1x = kx[e], e1z = kz[e];
    float e2x = kx[(e + 1) & 3], e2z = kz[(e + 1) & 3];
    float ex = e2x - e1x, ez = e2z - e1z;
    int cnt = count > 1 ? count : 1;
    int lim = count < 8 ? count : 8;
    float ox[8] = {}, oz[8] = {};
    int p = 0;
#pragma unroll
    for (int idx = 0; idx < 8; ++idx) {
      if (idx < lim) {
        const int nis = (idx + 1 > 7) ? 7 : idx + 1;  // compile-time index
        float nx = px[nis], nz = pz[nis];
        if (idx + 1 == cnt) { nx = px[0]; nz = pz[0]; }
        float cx = px[idx], cz = pz[idx];
        float dc = ex * (cz - e1z) - ez * (cx - e1x);
        float dn = ex * (nz - e1z) - ez * (nx - e1x);
        bool ic = dc >= 0.f, in_ = dn >= 0.f;
        if (ic) {
          poly_ins(ox, oz, p, cx, cz);
          ++p;
        }
        if (ic != in_) {
          float den = dc - dn;
          float t = dc / (fabsf(den) < 1e-9f ? 1e-9f : den);
          poly_ins(ox, oz, p, cx + t * (nx - cx), cz + t * (nz - cz));
          ++p;
        }
      }
    }
    count = p;
    int cp = p < 8 ? p : 8;
#pragma unroll
    for (int i = 0; i < 8; ++i) {
      px[i] = (i < cp) ? ox[i] : 0.f;
      pz[i] = (i < cp) ? oz[i] : 0.f;
    }
  }
  int cnt = count > 1 ? count : 1;
  int lim = count < 8 ? count : 8;
  float ssum = 0.f;
#pragma unroll
  for (int idx = 0; idx < 8; ++idx) {
    if (idx < lim) {
      const int nis = (idx + 1 > 7) ? 7 : idx + 1;
      float nx = px[nis], nz = pz[nis];
      if (idx + 1 == cnt) { nx = px[0]; nz = pz[0]; }
      ssum += px[idx] * nz - nx * pz[idx];
    }
  }
  float inter = 0.5f * fabsf(ssum);
  return inter / fmaxf(garea + 10.f - inter, 1e-8f);
}

// ---------------- fused: conv3 (512 blk) | iou (1600 blk) | prep_w1 (128 blk)
__global__ __launch_bounds__(256) void fused_mid(
    const float* __restrict__ in2, const float* __restrict__ w3,
    const float* __restrict__ b3, const float* __restrict__ aff2,
    float* __restrict__ out3T,
    const float* __restrict__ points, const float* __restrict__ gt,
    float* __restrict__ iou10, float* __restrict__ o_gt, int* __restrict__ rank,
    const float* __restrict__ w1, unsigned short* __restrict__ W1f) {
  __shared__ __align__(16) float sB[64][68];
  __shared__ __align__(16) float sWT[64][68];
  const int bid = blockIdx.x;
  const int tid = threadIdx.x;
  if (bid < 512) {
    // ---- conv3: C=128, O=256, AFF+RELU, TRANS ----
    const int i0 = (bid & 15) * 64;
    const int o0 = ((bid >> 4) & 3) * 64;
    const int b = bid >> 6;
    const int tk = tid & 15, to = tid >> 4;
    float acc[4][4] = {};
    for (int c0 = 0; c0 < 128; c0 += 64) {
      for (int idx = tid; idx < 4096; idx += 256) {
        int ii = idx & 63, cc = idx >> 6;
        int c = c0 + cc;
        float v = in2[(b * 128 + c) * 1024 + i0 + ii];
        v = fmaf(v, aff2[c], aff2[128 + c]);
        v = fmaxf(v, 0.f);
        sB[cc][ii] = v;
      }
      for (int idx = tid; idx < 4096; idx += 256) {
        int cc = idx & 63, oo = idx >> 6;
        sWT[cc][oo] = w3[(o0 + oo) * 128 + c0 + cc];
      }
      __syncthreads();
      for (int cc = 0; cc < 64; ++cc) { FMA16(); }
      __syncthreads();
    }
    float c0v = b3[o0 + to * 4], c1v = b3[o0 + to * 4 + 1];
    float c2v = b3[o0 + to * 4 + 2], c3v = b3[o0 + to * 4 + 3];
#pragma unroll
    for (int jj = 0; jj < 4; ++jj) {
      float4 v = make_float4(acc[0][jj] + c0v, acc[1][jj] + c1v, acc[2][jj] + c2v, acc[3][jj] + c3v);
      *(float4*)&out3T[((size_t)(b * 1024) + i0 + tk * 4 + jj) * 256 + o0 + to * 4] = v;
    }
  } else if (bid < 2112) {
#pragma clang fp contract(off)
    // ---- iou + folded init (rank zero + o_gt copy) ----
    int r = bid - 512;
    int g = r / 160;
    int rb = r % 160;
    int b = rb / 20;
    int axb = rb % 20;
    int a = axb * 256 + tid;
    if (g == 0) rank[b * 5120 + a] = 0;
    if (g == 0 && b == 0 && axb == 0 && tid < 90)
      o_gt[tid] = gt[630 + tid];
    const float* L = gt + b * 90 + g * 9;
    float gxx = L[3], gzz = L[5], gw = L[0], gl = L[2], gth = L[6];
    float c = cosf(gth), s = sinf(gth);
    const float sx[4] = {0.5f, -0.5f, -0.5f, 0.5f};
    const float sz[4] = {0.5f, 0.5f, -0.5f, -0.5f};
    float gcx[4], gcz[4];
#pragma unroll
    for (int k = 0; k < 4; ++k) {
      float lx = sx[k] * gw, lz = sz[k] * gl;
      gcx[k] = gxx + lx * c - lz * s;
      gcz[k] = gzz + lx * s + lz * c;
    }
    float garea = gw * gl;
    int pt = a / 5, j = a % 5;
    const float CX[5] = {0.f, 0.f, 2.5f, 2.5f, 2.5f};
    const float CZ[5] = {1.f, -1.f, -1.f, 1.f, 0.f};
    const float* P = points + b * 4096;
    float ax = P[pt] - CX[j];
    float az = P[2048 + pt] - CZ[j];
    iou10[(size_t)(b * 10 + g) * 5120 + a] = bev_iou_ga(gcx, gcz, garea, ax, az);
  } else {
    // ---- prep_w1: 4 outputs per block, 64 lanes each ----
    int o = (bid - 2112) * 4 + (tid >> 6);
    int lp = tid & 63;
    if (lp < 36) {
      int ks = lp >> 2, quad = lp & 3;
      int tile = o >> 4;
      union { __hip_bfloat16 h[8]; uint4 u; } pk;
#pragma unroll
      for (int j = 0; j < 8; ++j) {
        int c = ks * 32 + quad * 8 + j;
        float v = (c < 259) ? w1[o * 259 + c] : 0.f;
        pk.h[j] = __float2bfloat16(v);
      }
      *(uint4*)&W1f[((size_t)(tile * 9 + ks) * 64 + quad * 16 + (o & 15)) * 8] = pk.u;
    }
  }
}

// ---------------- fused: bn_stats_t (256 blk) | iou_reduce (160 blk) --------
__global__ __launch_bounds__(256) void bn_iou_red(
    const float* __restrict__ x, const float* __restrict__ g,
    const float* __restrict__ be, float* __restrict__ aff,
    const float* __restrict__ iou10, float* __restrict__ maxiou,
    int* __restrict__ maxind) {
  const int bid = blockIdx.x;
  const int tid = threadIdx.x;
  if (bid < 256) {
#pragma clang fp contract(off)
    int c = bid;
    float s = 0.f, q = 0.f;
    for (int idx = tid; idx < 8192; idx += 256) {
      float v = x[(size_t)idx * 256 + c];
      s += v;
      q += v * v;
    }
    for (int m = 1; m < 64; m <<= 1) {
      s += __shfl_xor(s, m);
      q += __shfl_xor(q, m);
    }
    __shared__ float as_[4], aq_[4];
    int wv = tid >> 6;
    if ((tid & 63) == 0) { as_[wv] = s; aq_[wv] = q; }
    __syncthreads();
    if (tid == 0) {
      s = as_[0] + as_[1] + as_[2] + as_[3];
      q = aq_[0] + aq_[1] + aq_[2] + aq_[3];
      float m_ = s * (1.f / 8192.f);
      float var = q * (1.f / 8192.f) - m_ * m_;
      float A = g[c] / sqrtf(var + 1e-5f);
      aff[c] = A;
      aff[256 + c] = be[c] - m_ * A;
    }
  } else {
    int r = bid - 256;
    int b = r / 20;
    int a = (r % 20) * 256 + tid;
    float best = -1.f;
    int bi = 0;
    for (int g2 = 0; g2 < 10; ++g2) {
      float v = iou10[(size_t)(b * 10 + g2) * 5120 + a];
      if (v > best) { best = v; bi = g2; }
    }
    maxiou[b * 5120 + a] = best;
    maxind[b * 5120 + a] = bi;
  }
}

// ---------------- rank: partial counts over j-chunks (round-15 form) --------
__global__ __launch_bounds__(256) void select_rank(const float* __restrict__ maxiou,
                                                   int* __restrict__ rank) {
  __shared__ __align__(16) float vals[640];
  int b = blockIdx.y, chunk = blockIdx.z, tid = threadIdx.x;
  int jb0 = chunk * 640;
  for (int i = tid; i < 640; i += 256) vals[i] = maxiou[b * 5120 + jb0 + i];
  int a = blockIdx.x * 256 + tid;
  float av = maxiou[b * 5120 + a];
  __syncthreads();
  int rk = 0;
#pragma unroll 4
  for (int j4 = 0; j4 < 160; ++j4) {
    float4 v = *(const float4*)&vals[j4 * 4];
    int jb = jb0 + j4 * 4;
    rk += (v.x < av) || (v.x == av && jb < a);
    rk += (v.y < av) || (v.y == av && jb + 1 < a);
    rk += (v.z < av) || (v.z == av && jb + 2 < a);
    rk += (v.w < av) || (v.w == av && jb + 3 < a);
  }
  atomicAdd(&rank[b * 5120 + a], rk);
}

// ---------------- write selected rows from final ranks ----------------------
__global__ __launch_bounds__(256) void select_write(const int* __restrict__ rank,
                                                    const float* __restrict__ maxiou,
                                                    const int* __restrict__ maxind,
                                                    const float* __restrict__ points,
                                                    float* __restrict__ o_lbl,
                                                    float* __restrict__ o_iou,
                                                    float* __restrict__ o_box,
                                                    float* __restrict__ o_idx) {
#pragma clang fp contract(off)
  int b = blockIdx.y, tid = threadIdx.x;
  int a = blockIdx.x * 256 + tid;
  int rk = rank[b * 5120 + a];
  int slot = -1;
  if (rk < 64) slot = rk;
  else if (rk >= 5056) slot = rk - 4992;  // 64 + (rk - 5056)
  if (slot >= 0) {
    const float CX[5] = {0.f, 0.f, 2.5f, 2.5f, 2.5f};
    const float CZ[5] = {1.f, -1.f, -1.f, 1.f, 0.f};
    int base = b * 128 + slot;
    float av = maxiou[b * 5120 + a];
    o_iou[base] = av;
    o_lbl[base] = av > 0.5f ? 1.f : 0.f;
    o_idx[base] = (float)maxind[b * 5120 + a];
    int pt = a / 5, j = a % 5;
    const float* P = points + b * 4096;
    float* bx = o_box + base * 7;
    bx[0] = P[pt] - CX[j];
    bx[1] = P[1024 + pt];
    bx[2] = P[2048 + pt] - CZ[j];
    bx[3] = 2.f;
    bx[4] = 2.f;
    bx[5] = 5.f;
    bx[6] = 0.f;
  }
}

// ---- pool inside-test, fp-contract off (bit-exact vs old pool_kernel) ------
__device__ __forceinline__ bool pool_inside(const float* __restrict__ P,
                                            const float* bx, int pt) {
#pragma clang fp contract(off)
  float limx = bx[4] * 0.5f + 0.2f, limz = bx[5] * 0.5f + 0.2f;
  float ylo = bx[1] - bx[3] - 0.2f, yhi = bx[1] + 0.2f;
  float dx = P[pt] - bx[0];
  float py = P[1024 + pt];
  float dz = P[2048 + pt] - bx[2];
  return (fabsf(dx) < limx) && (fabsf(dz) < limz) && (py > ylo) && (py < yhi);
}

// ---------------- fused pool + gather + rp1 (pff lives only in LDS) ---------
__global__ __launch_bounds__(1024) void gather_rp1(
    const float* __restrict__ out3T, const float* __restrict__ points,
    const float* __restrict__ selboxes, const float* __restrict__ aff3,
    const float* __restrict__ bias1, const unsigned short* __restrict__ W1f,
    unsigned short* __restrict__ g1x,
    float* __restrict__ psum4, float* __restrict__ psq4) {
  __shared__ __align__(16) unsigned short sBuf[18432];  // 36KB B-tile
  __shared__ int sSel[64];
  __shared__ float sBox[8];
  __shared__ float sA3[256], sB3[256];
  __shared__ int wcnt[16];
  const int bm = blockIdx.x;
  const int b = bm >> 7;
  const int tid = threadIdx.x;
  if (tid < 7) sBox[tid] = selboxes[bm * 7 + tid];
  if (tid >= 256 && tid < 512) sA3[tid - 256] = aff3[tid - 256];
  if (tid >= 512 && tid < 768) sB3[tid - 512] = aff3[256 + tid - 512];
  __syncthreads();
  // -------- phase 0: pool (pt = tid, 16 waves x 64 lanes) --------
  {
    const float* P = points + b * 4096;
    const int lane = tid & 63, w16 = tid >> 6;
    bool ins = pool_inside(P, sBox, tid);
    unsigned long long mw = __ballot(ins);
    if (lane == 0) wcnt[w16] = __popcll(mw);
    __syncthreads();
    int cumw = 0, total = 0;
#pragma unroll
    for (int i = 0; i < 16; ++i) {
      int c = wcnt[i];
      total += c;
      if (i < w16) cumw += c;
    }
    int inbefore = cumw + __popcll(mw & ((1ull << lane) - 1));
    int slot = ins ? inbefore : total + (tid - inbefore);
    if (slot < 64) sSel[slot] = tid | (ins ? 0x10000 : 0);
    __syncthreads();
  }
  // -------- phase 1: gather into LDS --------
  for (int u = tid; u < 2304; u += 1024) {
    int ks, pool, part;
    if (u < 2048) {
      ks = u >> 8;
      int rem = u & 255;
      pool = rem >> 2;
      part = rem & 3;
    } else {
      int v = u - 2048;
      ks = 8;
      pool = v >> 2;
      part = v & 3;
    }
    const int ni = pool >> 4, nib = pool & 15;
    const int sv = sSel[pool];
    const int pt = sv & 0xFFFF;
    const bool valid = (sv >> 16) != 0;
    union { __hip_bfloat16 h[8]; uint4 uu; } pk;
    if (ks < 8) {
      const float* row = out3T + ((size_t)(b << 10) + pt) * 256;
      int c0 = ks * 32 + part * 8;
      float4 x0 = *(const float4*)&row[c0];
      float4 x1 = *(const float4*)&row[c0 + 4];
      float v[8] = {x0.x, x0.y, x0.z, x0.w, x1.x, x1.y, x1.z, x1.w};
#pragma unroll
      for (int e = 0; e < 8; ++e) {
        float vv = valid ? fmaf(v[e], sA3[c0 + e], sB3[c0 + e]) : 0.f;
        pk.h[e] = __float2bfloat16(vv);
      }
    } else {
#pragma unroll
      for (int e = 0; e < 8; ++e) pk.h[e] = __float2bfloat16(0.f);
      if (part == 0) {
#pragma unroll
        for (int d = 0; d < 3; ++d) {
          float pv = valid ? points[(b * 4 + d) * 1024 + pt] : 0.f;
          pk.h[d] = __float2bfloat16(pv - sBox[d]);
        }
      }
    }
    *(uint4*)&sBuf[(size_t)(((ks * 4 + ni) * 64) + part * 16 + nib) * 8] = pk.uu;
  }
  __syncthreads();
  // -------- phase 2: rp1 MFMA (16 waves, mi=2) --------
  const int lane = tid & 63, wv = tid >> 6;
  const int ot = wv >> 2, w = wv & 3;
  const int quad = lane >> 4, nib = lane & 15;
  const unsigned short* Aw = &W1f[((size_t)(ot * 8 + w * 2) * 9 * 64 + lane) * 8];
  const unsigned short* Bl = &sBuf[lane * 8];
  f32x4 acc[2][4] = {};
#pragma unroll
  for (int ks = 0; ks < 9; ++ks) {
    short8 af[2], bf[4];
#pragma unroll
    for (int mi = 0; mi < 2; ++mi)
      af[mi] = *(const short8*)&Aw[(size_t)(mi * 9 + ks) * 512];
#pragma unroll
    for (int ni = 0; ni < 4; ++ni)
      bf[ni] = *(const short8*)&Bl[(size_t)(ks * 4 + ni) * 512];
#pragma unroll
    for (int mi = 0; mi < 2; ++mi)
#pragma unroll
      for (int ni = 0; ni < 4; ++ni)
        acc[mi][ni] = __builtin_amdgcn_mfma_f32_16x16x32_bf16(af[mi], bf[ni], acc[mi][ni], 0, 0, 0);
  }
  const int cbase = ot * 128 + w * 32;
#pragma unroll
  for (int mi = 0; mi < 2; ++mi) {
    float bv[4];
#pragma unroll
    for (int r = 0; r < 4; ++r) bv[r] = bias1[cbase + mi * 16 + quad * 4 + r];
    float s[4] = {0.f, 0.f, 0.f, 0.f}, q[4] = {0.f, 0.f, 0.f, 0.f};
    const int kgbase = (cbase + mi * 16) >> 3;
#pragma unroll
    for (int ni = 0; ni < 4; ++ni) {
      union { __hip_bfloat16 h[4]; unsigned int u[2]; } pk;
#pragma unroll
      for (int r = 0; r < 4; ++r) {
        float v = acc[mi][ni][r] + bv[r];
        pk.h[r] = __float2bfloat16(v);
        s[r] += v;
        q[r] += v * v;
      }
      unsigned int p0 = (unsigned int)__shfl_xor((int)pk.u[0], 16);
      unsigned int p1 = (unsigned int)__shfl_xor((int)pk.u[1], 16);
      if ((quad & 1) == 0) {
        uint4 g = make_uint4(pk.u[0], pk.u[1], p0, p1);
        int kg = kgbase + (quad >> 1);
        *(uint4*)&g1x[((size_t)(bm * 64 + kg) * 64 + ni * 16 + nib) * 8] = g;
      }
    }
#pragma unroll
    for (int r = 0; r < 4; ++r) {
      float ss = dpp_sum16(s[r]);
      float qq = dpp_sum16(q[r]);
      if (nib == 0) {
        int o = cbase + mi * 16 + quad * 4 + r;
        psum4[(size_t)o * 1024 + bm] = ss;
        psq4[(size_t)o * 1024 + bm] = qq;
      }
    }
  }
}

// ---------------- BN affine from per-bm partials, [o][bm] layout ------------
__global__ __launch_bounds__(64) void bn_aff_part(const float* __restrict__ psum,
                                                  const float* __restrict__ psq,
                                                  const float* __restrict__ g,
                                                  const float* __restrict__ be,
                                                  float* __restrict__ aff, int C) {
#pragma clang fp contract(off)
  int o = blockIdx.x;
  int lane = threadIdx.x;
  float s = 0.f, q = 0.f;
  for (int i = 0; i < 16; ++i) {
    int bm = i * 64 + lane;
    s += psum[(size_t)o * 1024 + bm];
    q += psq[(size_t)o * 1024 + bm];
  }
  for (int m = 1; m < 64; m <<= 1) {
    s += __shfl_xor(s, m);
    q += __shfl_xor(q, m);
  }
  if (lane == 0) {
    float m_ = s * (1.f / 65536.f);
    float var = q * (1.f / 65536.f) - m_ * m_;
    float A = g[o] / sqrtf(var + 1e-5f);
    aff[o] = A;
    aff[C + o] = be[o] - m_ * A;
  }
}

// ---------------- prep W2: fold BN4, A-fragment order [tile64][ks16][lane][8]
__global__ __launch_bounds__(64) void prep_w2(const float* __restrict__ w2,
                                              const float* __restrict__ b2,
                                              const float* __restrict__ aff4,
                                              unsigned short* __restrict__ W2f,
                                              float* __restrict__ bias2p) {
  int o = blockIdx.x;
  int lp = threadIdx.x;
  int ks = lp >> 2, quad = lp & 3;
  int tile = o >> 4;
  float accb = 0.f;
  union { __hip_bfloat16 h[8]; uint4 u; } pk;
#pragma unroll
  for (int j = 0; j < 8; ++j) {
    int c = ks * 32 + quad * 8 + j;
    float wv = w2[o * 512 + c];
    pk.h[j] = __float2bfloat16(wv * aff4[c]);
    accb += wv * aff4[512 + c];
  }
  *(uint4*)&W2f[((size_t)(tile * 16 + ks) * 64 + quad * 16 + (o & 15)) * 8] = pk.u;
  for (int m = 1; m < 64; m <<= 1) accb += __shfl_xor(accb, m);
  if (lp == 0) bias2p[o] = b2[o] + accb;
}

// ---------------- rp2: round-8 exact (best measured); psum [o][bm] ----------
__global__ __launch_bounds__(256) void rp2_mfma(const unsigned short* __restrict__ W2f,
                                                const unsigned short* __restrict__ g1x,
                                                const float* __restrict__ bias2p,
                                                float* __restrict__ maxb,
                                                float* __restrict__ minb,
                                                float* __restrict__ psum,
                                                float* __restrict__ psq) {
  // 4 chunks x 4 ks; chunk = 4*2048 shorts = 16KB; double buffer = 32KB LDS
  __shared__ __align__(16) unsigned short sBuf[2][8192];
  const int tid = threadIdx.x;
  const int lane = tid & 63, w = tid >> 6;
  const int quad = lane >> 4, nib = lane & 15;
  const int l = blockIdx.x;            // 4096 blocks
  const int xcd = l & 7;
  const int j = l >> 3;                // 0..511
  const int ot = j & 3;
  const int bm = xcd * 128 + (j >> 2);
  const unsigned short* Aw = &W2f[((size_t)(ot * 4 + w) * 4 * 16 * 64 + lane) * 8];
  const unsigned short* Bg = g1x + (size_t)bm * 32768 + w * 2048 + lane * 8;
#pragma unroll
  for (int i = 0; i < 4; ++i)
    stage1k(Bg + i * 512, &sBuf[0][w * 2048 + i * 512]);
  __syncthreads();
  f32x4 acc[4][4] = {};  // acc[pi][oi]: rows = pools, cols = o
  int cur = 0;
#pragma unroll
  for (int c = 0; c < 4; ++c) {
    if (c < 3) {
#pragma unroll
      for (int i = 0; i < 4; ++i)
        stage1k(Bg + (c + 1) * 8192 + i * 512, &sBuf[cur ^ 1][w * 2048 + i * 512]);
    }
    const unsigned short* Bl = &sBuf[cur][quad * 512 + nib * 8];
#pragma unroll
    for (int k2 = 0; k2 < 4; ++k2) {
      const int ks = c * 4 + k2;
      short8 af[4], bf[4];
#pragma unroll
      for (int mi = 0; mi < 4; ++mi)
        af[mi] = *(const short8*)&Aw[(size_t)(mi * 16 + ks) * 512];
#pragma unroll
      for (int ni = 0; ni < 4; ++ni)
        bf[ni] = *(const short8*)&Bl[(size_t)(k2 * 2048 + ni * 128)];
#pragma unroll
      for (int mi = 0; mi < 4; ++mi)
#pragma unroll
        for (int ni = 0; ni < 4; ++ni)
          acc[ni][mi] = __builtin_amdgcn_mfma_f32_16x16x32_bf16(bf[ni], af[mi], acc[ni][mi], 0, 0, 0);
    }
    __syncthreads();
    cur ^= 1;
  }
  const int obase = ot * 256 + w * 64;
#pragma unroll
  for (int oi = 0; oi < 4; ++oi) {
    int o = obase + oi * 16 + nib;
    float bs = bias2p[o];
    float mx = -FLT_MAX, mn = FLT_MAX, s = 0.f, q = 0.f;
#pragma unroll
    for (int pi = 0; pi < 4; ++pi) {
#pragma unroll
      for (int r = 0; r < 4; ++r) {
        float v = acc[pi][oi][r] + bs;
        mx = fmaxf(mx, v);
        mn = fminf(mn, v);
        s += v;
        q += v * v;
      }
    }
    mx = fmaxf(mx, __shfl_xor(mx, 16));
    mx = fmaxf(mx, __shfl_xor(mx, 32));
    mn = fminf(mn, __shfl_xor(mn, 16));
    mn = fminf(mn, __shfl_xor(mn, 32));
    s += __shfl_xor(s, 16);
    s += __shfl_xor(s, 32);
    q += __shfl_xor(q, 16);
    q += __shfl_xor(q, 32);
    if (quad == 0) {
      maxb[bm * 1024 + o] = mx;
      minb[bm * 1024 + o] = mn;
      psum[(size_t)o * 1024 + bm] = s;
      psq[(size_t)o * 1024 + bm] = q;
    }
  }
}

// ---------------- feats: monotone-affine max over NPOOL --------------------
__global__ void feats_kernel(const float* __restrict__ maxb, const float* __restrict__ minb,
                             const float* __restrict__ aff5, float* __restrict__ o_feats) {
#pragma clang fp contract(off)
  int i = blockIdx.x * 256 + threadIdx.x;
  int o = i & 1023;
  float A = aff5[o], Bv = aff5[1024 + o];
  float v = (A >= 0.f) ? maxb[i] : minb[i];
  o_feats[i] = v * A + Bv;
}

// ---------------------------------------------------------------------------
extern "C" void kernel_launch(void* const* d_in, const int* in_sizes, int n_in,
                              void* d_out, int out_size, void* d_ws, size_t ws_size,
                              hipStream_t stream) {
  (void)in_sizes; (void)n_in; (void)out_size; (void)ws_size;
  const float* points = (const float*)d_in[0];
  const float* gt = (const float*)d_in[1];
  const float* pn_w1 = (const float*)d_in[2];
  const float* pn_b1 = (const float*)d_in[3];
  const float* pn_g1 = (const float*)d_in[4];
  const float* pn_be1 = (const float*)d_in[5];
  const float* pn_w2 = (const float*)d_in[6];
  const float* pn_b2 = (const float*)d_in[7];
  const float* pn_g2 = (const float*)d_in[8];
  const float* pn_be2 = (const float*)d_in[9];
  const float* pn_w3 = (const float*)d_in[10];
  const float* pn_b3 = (const float*)d_in[11];
  const float* pn_g3 = (const float*)d_in[12];
  const float* pn_be3 = (const float*)d_in[13];
  const float* rp_w1 = (const float*)d_in[14];
  const float* rp_b1 = (const float*)d_in[15];
  const float* rp_g1 = (const float*)d_in[16];
  const float* rp_be1 = (const float*)d_in[17];
  const float* rp_w2 = (const float*)d_in[18];
  const float* rp_b2 = (const float*)d_in[19];
  const float* rp_g2 = (const float*)d_in[20];
  const float* rp_be2 = (const float*)d_in[21];

  float* ws = (float*)d_ws;
  float* out1 = ws;                        // 524288 f (reused: W2f+bias2p)
  float* out2 = out1 + 524288;             // 1048576 f
  float* maxiou = out2 + 1048576;          // 40960
  int* maxind = (int*)(maxiou + 40960);    // 40960
  int* selpts = maxind + 40960;            // 65536 (unused)
  int* rank = selpts + 65536;              // 40960
  float* aff1 = (float*)(rank + 40960);    // 128
  float* aff2 = aff1 + 128;                // 256
  float* aff3 = aff2 + 256;                // 512
  float* aff4 = aff3 + 512;                // 1024
  float* aff5 = aff4 + 1024;               // 2048
  float* psum4 = aff5 + 2048;              // 524288
  float* psq4 = psum4 + 524288;            // 524288
  unsigned short* W1f = (unsigned short*)(psq4 + 524288);  // 147456 sh = 73728 f
  float* pff_f = (float*)(W1f) + 73728;    // 9437184 f region (pff now LDS-only)
  float* out3T = pff_f;                    // 2097152 f — disjoint from g1x
  float* maxb = pff_f + 2097152;           // 4x1048576 f, after out3T
  float* minb = maxb + 1048576;
  float* psum5 = minb + 1048576;
  float* psq5 = psum5 + 1048576;
  float* g1x_f = pff_f + 9437184;          // g1x: 16777216 f
  unsigned short* g1x = (unsigned short*)g1x_f;
  float* iou10 = g1x_f + 2097152;          // 409600 f, overlaps g1x (dead before gather_rp1)
  unsigned short* W2f = (unsigned short*)out1;
  float* bias2p = out1 + 262144;

  float* o_feats = (float*)d_out;
  float* o_lbl = o_feats + 1048576;
  float* o_iou = o_lbl + 1024;
  float* o_box = o_iou + 1024;
  float* o_gt = o_box + 7168;
  float* o_idx = o_gt + 90;

  conv_pn<4, 64, false, false, false><<<dim3(16, 1, 8), 256, 0, stream>>>(points, pn_w1, pn_b1, nullptr, out1);
  bn_stats<<<64, 256, 0, stream>>>(out1, pn_g1, pn_be1, aff1, 64);
  conv_pn<64, 128, true, true, false><<<dim3(16, 2, 8), 256, 0, stream>>>(out1, pn_w2, pn_b2, aff1, out2);
  bn_stats<<<128, 256, 0, stream>>>(out2, pn_g2, pn_be2, aff2, 128);
  fused_mid<<<2240, 256, 0, stream>>>(out2, pn_w3, pn_b3, aff2, out3T,
                                      points, gt, iou10, o_gt, rank,
                                      rp_w1, W1f);
  bn_iou_red<<<416, 256, 0, stream>>>(out3T, pn_g3, pn_be3, aff3,
                                      iou10, maxiou, maxind);
  select_rank<<<dim3(20, 8, 8), 256, 0, stream>>>(maxiou, rank);
  select_write<<<dim3(20, 8), 256, 0, stream>>>(rank, maxiou, maxind, points, o_lbl, o_iou, o_box, o_idx);
  gather_rp1<<<1024, 1024, 0, stream>>>(out3T, points, o_box, aff3,
                                        rp_b1, W1f, g1x, psum4, psq4);
  bn_aff_part<<<512, 64, 0, stream>>>(psum4, psq4, rp_g1, rp_be1, aff4, 512);
  prep_w2<<<1024, 64, 0, stream>>>(rp_w2, rp_b2, aff4, W2f, bias2p);
  rp2_mfma<<<4096, 256, 0, stream>>>(W2f, g1x, bias2p, maxb, minb, psum5, psq5);
  bn_aff_part<<<1024, 64, 0, stream>>>(psum5, psq5, rp_g2, rp_be2, aff5, 1024);
  feats_kernel<<<4096, 256, 0, stream>>>(maxb, minb, aff5, o_feats);
}